// Round 3
// baseline (207.364 us; speedup 1.0000x reference)
//
#include <hip/hip_runtime.h>
#include <stdint.h>
#include <math.h>

#define NOPS 37

struct Ops37 {
    int type[NOPS];  // 0 rx, 1 ry, 2 rz, 3 cnot, 4 H, 5 SX
    int a[NOPS];     // wire (rot/H/SX) or control (cnot)
    int b[NOPS];     // target (cnot), else -1
};

// ---------------------------------------------------------------------------
// Host-side exact replication of np.random.default_rng(42) for _random_ops().
// SeedSequence(42) -> PCG64 -> Generator.
//   FIX (round 2): SeedSequence mix(x,y) = (x*MIX_MULT_L) - (y*MIX_MULT_R),
//   then ^= >>16 — SUBTRACTION (randutils lineage), not XOR. Rounds 0/1 used
//   XOR -> garbage pool -> garbage ops; their shuffle A/B told us nothing.
//   integers:      _rand_int64 -> random_bounded_uint64_fill -> Lemire-32
//   choice vals:   random_bounded_uint64 (use_masked=0) -> Lemire-32
//   choice tail:   _shuffle_int -> random_bounded_uint64 -> Lemire-32
//       (i=1 -> top bit of one 32-bit word)
// next_uint32 = pcg64_next32: 32-bit halves of pcg64_next64, LOW word first,
// high word buffered (has_uint32/uinteger).
// Ledger if wrong: (a) shuffle via random_interval low-bit; (b) scalar
// bounded_uint64 without 32-bit downshift; (c) next32 high-word-first.
// ---------------------------------------------------------------------------
static void build_ops_host(Ops37* ops) {
    // ---- SeedSequence(42): pool of 4 uint32 ----
    uint32_t pool[4];
    uint32_t hc = 0x43b0d7e5u;  // INIT_A
    auto hmix = [&hc](uint32_t value) -> uint32_t {
        value ^= hc;
        hc *= 0x931e8875u;      // MULT_A
        value *= hc;
        value ^= value >> 16;
        return value;
    };
    auto mixf = [](uint32_t x, uint32_t y) -> uint32_t {
        uint32_t r = (x * 0xca01f9ddu) - (y * 0x4973f715u);  // SUBTRACTION
        r ^= r >> 16;
        return r;
    };
    pool[0] = hmix(42u);
    for (int i = 1; i < 4; i++) pool[i] = hmix(0u);
    for (int s = 0; s < 4; s++)
        for (int d = 0; d < 4; d++)
            if (s != d) pool[d] = mixf(pool[d], hmix(pool[s]));

    // ---- generate_state(4, uint64) -> 8 uint32 words, paired little-endian
    uint32_t st[8];
    {
        uint32_t hcb = 0x8b51f9ddu;  // INIT_B
        for (int i = 0; i < 8; i++) {
            uint32_t dv = pool[i & 3];
            dv ^= hcb;
            hcb *= 0x58f38dedu;      // MULT_B
            dv *= hcb;
            dv ^= dv >> 16;
            st[i] = dv;
        }
    }
    typedef __uint128_t u128;
    const uint64_t v0 = (uint64_t)st[0] | ((uint64_t)st[1] << 32);
    const uint64_t v1 = (uint64_t)st[2] | ((uint64_t)st[3] << 32);
    const uint64_t v2 = (uint64_t)st[4] | ((uint64_t)st[5] << 32);
    const uint64_t v3 = (uint64_t)st[6] | ((uint64_t)st[7] << 32);
    const u128 initstate = (((u128)v0) << 64) | v1;  // seed[0] is HIGH
    const u128 initseq   = (((u128)v2) << 64) | v3;
    const u128 MULT = (((u128)0x2360ed051fc65da4ULL) << 64) | 0x4385df649fccf645ULL;

    u128 state = 0;
    const u128 inc = (initseq << 1) | 1;
    state = state * MULT + inc;
    state += initstate;
    state = state * MULT + inc;

    bool has32 = false;
    uint32_t cached = 0;
    auto next64 = [&]() -> uint64_t {
        state = state * MULT + inc;  // step first, then XSL-RR output
        uint64_t hi = (uint64_t)(state >> 64);
        uint64_t lo = (uint64_t)state;
        unsigned rot = (unsigned)(state >> 122) & 63u;
        uint64_t v = hi ^ lo;
        return (v >> rot) | (v << ((64u - rot) & 63u));
    };
    auto next32 = [&]() -> uint32_t {
        if (has32) { has32 = false; return cached; }
        uint64_t n = next64();
        has32 = true;
        cached = (uint32_t)(n >> 32);  // high word buffered
        return (uint32_t)n;            // low word first
    };
    auto lem = [&](uint32_t rng) -> uint32_t {  // Lemire32, uniform on [0, rng]
        const uint32_t rng_excl = rng + 1u;
        uint64_t m = (uint64_t)next32() * (uint64_t)rng_excl;
        uint32_t leftover = (uint32_t)m;
        if (leftover < rng_excl) {
            const uint32_t threshold = (0xFFFFFFFFu - rng) % rng_excl;
            while (leftover < threshold) {
                m = (uint64_t)next32() * (uint64_t)rng_excl;
                leftover = (uint32_t)m;
            }
        }
        return (uint32_t)(m >> 32);
    };

    for (int k = 0; k < 30; k++) {
        uint32_t g = lem(3);            // integers(0,4)
        if (g == 3u) {
            // choice(4, size=2, replace=False): Floyd's (j=2 then j=3), then
            // _shuffle_int(2,1): one Lemire-32 draw on [0,1] (top bit).
            uint32_t i0 = lem(2);       // j=2: val in [0,2] -> idx[0]
            uint32_t vv = lem(3);       // j=3: val in [0,3]
            uint32_t i1 = (vv == i0) ? 3u : vv;
            uint32_t j = lem(1);        // _shuffle_int: Lemire-32, top bit
            if (j == 0u) { uint32_t t = i0; i0 = i1; i1 = t; }
            ops->type[k] = 3; ops->a[k] = (int)i0; ops->b[k] = (int)i1;
        } else {
            uint32_t w = lem(3);        // integers(0,4) wire
            ops->type[k] = (int)g; ops->a[k] = (int)w; ops->b[k] = -1;
        }
    }
    // tail: RX(q_rx)@0, RY(q_ry)@1, RZ(q_rz)@2, CNOT(0,3), H@3, SX@2, CNOT(3,0)
    ops->type[30] = 0; ops->a[30] = 0; ops->b[30] = -1;
    ops->type[31] = 1; ops->a[31] = 1; ops->b[31] = -1;
    ops->type[32] = 2; ops->a[32] = 2; ops->b[32] = -1;
    ops->type[33] = 3; ops->a[33] = 0; ops->b[33] = 3;
    ops->type[34] = 4; ops->a[34] = 3; ops->b[34] = -1;
    ops->type[35] = 5; ops->a[35] = 2; ops->b[35] = -1;
    ops->type[36] = 3; ops->a[36] = 3; ops->b[36] = 0;
}

// ---------------------------------------------------------------------------
// Kernel 0: build the fixed 16x16 unitary U (everything after the encoding).
// Wire w lives on bit (3-w) of the flattened index b0*8+b1*4+b2*2+b3.
// 16 lanes, lane j owns column j.
// ---------------------------------------------------------------------------
__global__ __launch_bounds__(64) void build_u_kernel(
        const float* __restrict__ rl, const float* __restrict__ qrx,
        const float* __restrict__ qry, const float* __restrict__ qrz,
        float* __restrict__ Uout, Ops37 ops) {
    int j = threadIdx.x;
    if (j >= 16) return;
    double cr[16], ci[16];
    for (int i = 0; i < 16; i++) { cr[i] = (i == j) ? 1.0 : 0.0; ci[i] = 0.0; }
    for (int k = 0; k < NOPS; k++) {
        int t = ops.type[k];
        if (t == 3) {
            int mc = 8 >> ops.a[k], mt = 8 >> ops.b[k];
            for (int i = 0; i < 16; i++) {
                if ((i & mc) && !(i & mt)) {
                    int i2 = i | mt;
                    double tr = cr[i], ti = ci[i];
                    cr[i] = cr[i2]; ci[i] = ci[i2];
                    cr[i2] = tr;    ci[i2] = ti;
                }
            }
        } else {
            double g00r, g00i, g01r, g01i, g10r, g10i, g11r, g11i;
            if (t == 4) {          // H
                const double r = 0.70710678118654752440;
                g00r = r; g00i = 0; g01r = r;  g01i = 0;
                g10r = r; g10i = 0; g11r = -r; g11i = 0;
            } else if (t == 5) {   // SX = 0.5*[[1+i,1-i],[1-i,1+i]]
                g00r = 0.5; g00i = 0.5;  g01r = 0.5; g01i = -0.5;
                g10r = 0.5; g10i = -0.5; g11r = 0.5; g11i = 0.5;
            } else {
                float th = (k < 30) ? rl[k]
                         : (k == 30 ? qrx[0] : (k == 31 ? qry[0] : qrz[0]));
                double c = cos(0.5 * (double)th), s = sin(0.5 * (double)th);
                if (t == 0) {        // RX
                    g00r = c; g00i = 0;  g01r = 0; g01i = -s;
                    g10r = 0; g10i = -s; g11r = c; g11i = 0;
                } else if (t == 1) { // RY
                    g00r = c; g00i = 0; g01r = -s; g01i = 0;
                    g10r = s; g10i = 0; g11r = c;  g11i = 0;
                } else {             // RZ: diag(e^{-i t/2}, e^{+i t/2})
                    g00r = c; g00i = -s; g01r = 0; g01i = 0;
                    g10r = 0; g10i = 0;  g11r = c; g11i = s;
                }
            }
            int m = 8 >> ops.a[k];
            for (int i = 0; i < 16; i++) {
                if (!(i & m)) {
                    int i2 = i | m;
                    double ar = cr[i], ai = ci[i], br = cr[i2], bi = ci[i2];
                    cr[i]  = g00r * ar - g00i * ai + g01r * br - g01i * bi;
                    ci[i]  = g00r * ai + g00i * ar + g01r * bi + g01i * br;
                    cr[i2] = g10r * ar - g10i * ai + g11r * br - g11i * bi;
                    ci[i2] = g10r * ai + g10i * ar + g11r * bi + g11i * br;
                }
            }
        }
    }
    for (int i = 0; i < 16; i++) {
        Uout[2 * (i * 16 + j)]     = (float)cr[i];
        Uout[2 * (i * 16 + j) + 1] = (float)ci[i];
    }
}

// ---------------------------------------------------------------------------
// Kernel 1: fused per-sample forward. One block (128 threads) per sample.
// conv1(1->8,3x3,SAME)+relu+pool -> conv2(8->16)+relu+pool -> fc rows 0..3
// -> RX-encode product state -> chi = U*psi -> Pauli-Z exps[4].
// LDS layout (floats), 20.4 KB total:
//   W1 [0,72) B1 [72,80) W2 padded 9->12 [80,1616) B2 [1616,1632) FEAT [1632,1636)
//   region A [1636,2536): xp 30x30 (then reused as h2[784])
//   region B [2536,5096): h1 8x16x20 (rows padded to 20 to break the 128B
//   bank-conflict stride; later reused as RED[512]/PSI[32]/PV[16])
// ---------------------------------------------------------------------------
#define W1o   0
#define B1o   72
#define W2o   80
#define B2o   1616
#define FEATo 1632
#define XPo   1636
#define H2o   1636
#define H1o   2536
#define REDo  2536
#define PSIo  3056
#define PVo   3088
#define SMSZ  5104

__global__ __launch_bounds__(128) void fused_fwd_kernel(
        const float* __restrict__ x,
        const float* __restrict__ c1w, const float* __restrict__ c1b,
        const float* __restrict__ c2w, const float* __restrict__ c2b,
        const float* __restrict__ fcw, const float* __restrict__ fcb,
        const float* __restrict__ Ug, float* __restrict__ exps) {
    __shared__ __align__(16) float SM[SMSZ];
    const int tid = threadIdx.x;
    const int bidx = blockIdx.x;

    // ---- stage weights, x (zero-padded 30x30), zero h1 (incl. borders) ----
    for (int i = tid; i < 72; i += 128) SM[W1o + i] = c1w[i];
    if (tid < 8) SM[B1o + tid] = c1b[tid];
    for (int i = tid; i < 1152; i += 128) {
        int cc = i / 9, t = i - cc * 9;
        SM[W2o + cc * 12 + t] = c2w[i];
    }
    if (tid < 16) SM[B2o + tid] = c2b[tid];
    {
        const float* xb = x + (size_t)bidx * 784;
        for (int i = tid; i < 900; i += 128) {
            int r = i / 30, c = i - r * 30;
            float v = 0.f;
            if (r >= 1 && r <= 28 && c >= 1 && c <= 28) v = xb[(r - 1) * 28 + (c - 1)];
            SM[XPo + i] = v;
        }
    }
    for (int i = tid; i < 2560; i += 128) SM[H1o + i] = 0.f;
    __syncthreads();

    // ---- conv1 + relu + pool: 8 ch x 14x14 pooled outputs ----
    for (int o = tid; o < 1568; o += 128) {
        int c  = o / 196;
        int rem = o - c * 196;
        int py = rem / 14, px = rem - py * 14;
        float P[4][4];
        #pragma unroll
        for (int r = 0; r < 4; r++) {
            const float2 a  = *(const float2*)&SM[XPo + (2 * py + r) * 30 + 2 * px];
            const float2 b_ = *(const float2*)&SM[XPo + (2 * py + r) * 30 + 2 * px + 2];
            P[r][0] = a.x; P[r][1] = a.y; P[r][2] = b_.x; P[r][3] = b_.y;
        }
        float w[9];
        #pragma unroll
        for (int t = 0; t < 9; t++) w[t] = SM[W1o + c * 9 + t];
        float m = -3.4e38f;
        #pragma unroll
        for (int dy = 0; dy < 2; dy++)
            #pragma unroll
            for (int dx = 0; dx < 2; dx++) {
                float acc = 0.f;
                #pragma unroll
                for (int ky = 0; ky < 3; ky++)
                    #pragma unroll
                    for (int kx = 0; kx < 3; kx++)
                        acc = fmaf(P[dy + ky][dx + kx], w[ky * 3 + kx], acc);
                m = fmaxf(m, acc);
            }
        SM[H1o + c * 320 + (py + 1) * 20 + (px + 1)] = fmaxf(m + SM[B1o + c], 0.f);
    }
    __syncthreads();

    // ---- conv2 + relu + pool: thread = (c2,py) row, 7 pooled outputs ----
    if (tid < 112) {
        int c2 = tid / 7, py = tid - (tid / 7) * 7;
        float acc[7][4];
        #pragma unroll
        for (int px = 0; px < 7; px++)
            #pragma unroll
            for (int s = 0; s < 4; s++) acc[px][s] = 0.f;
        for (int c1 = 0; c1 < 8; c1++) {
            float R[4][16];
            #pragma unroll
            for (int r = 0; r < 4; r++) {
                #pragma unroll
                for (int q = 0; q < 4; q++) {
                    const float4 v = *(const float4*)&SM[H1o + c1 * 320 + (2 * py + r) * 20 + 4 * q];
                    R[r][4 * q + 0] = v.x; R[r][4 * q + 1] = v.y;
                    R[r][4 * q + 2] = v.z; R[r][4 * q + 3] = v.w;
                }
            }
            float w[9];
            {
                const float4 wa = *(const float4*)&SM[W2o + (c2 * 8 + c1) * 12];
                const float4 wb = *(const float4*)&SM[W2o + (c2 * 8 + c1) * 12 + 4];
                w[0] = wa.x; w[1] = wa.y; w[2] = wa.z; w[3] = wa.w;
                w[4] = wb.x; w[5] = wb.y; w[6] = wb.z; w[7] = wb.w;
                w[8] = SM[W2o + (c2 * 8 + c1) * 12 + 8];
            }
            #pragma unroll
            for (int px = 0; px < 7; px++)
                #pragma unroll
                for (int dy = 0; dy < 2; dy++)
                    #pragma unroll
                    for (int dx = 0; dx < 2; dx++) {
                        float a = acc[px][dy * 2 + dx];
                        #pragma unroll
                        for (int ky = 0; ky < 3; ky++)
                            #pragma unroll
                            for (int kx = 0; kx < 3; kx++)
                                a = fmaf(R[dy + ky][2 * px + dx + kx], w[ky * 3 + kx], a);
                        acc[px][dy * 2 + dx] = a;
                    }
        }
        const float bb = SM[B2o + c2];
        #pragma unroll
        for (int px = 0; px < 7; px++) {
            float m = fmaxf(fmaxf(acc[px][0], acc[px][1]), fmaxf(acc[px][2], acc[px][3]));
            SM[H2o + c2 * 49 + py * 7 + px] = fmaxf(m + bb, 0.f);
        }
    }
    __syncthreads();

    // ---- fc rows 0..3 (only feat[:, :4] is ever used) ----
    {
        float a0 = 0.f, a1 = 0.f, a2 = 0.f, a3 = 0.f;
        for (int j = tid; j < 784; j += 128) {
            float h = SM[H2o + j];
            a0 = fmaf(h, fcw[j],        a0);
            a1 = fmaf(h, fcw[784 + j],  a1);
            a2 = fmaf(h, fcw[1568 + j], a2);
            a3 = fmaf(h, fcw[2352 + j], a3);
        }
        SM[REDo + 0 * 128 + tid] = a0;
        SM[REDo + 1 * 128 + tid] = a1;
        SM[REDo + 2 * 128 + tid] = a2;
        SM[REDo + 3 * 128 + tid] = a3;
    }
    __syncthreads();
    for (int s = 64; s > 0; s >>= 1) {
        if (tid < s) {
            #pragma unroll
            for (int w = 0; w < 4; w++)
                SM[REDo + w * 128 + tid] += SM[REDo + w * 128 + tid + s];
        }
        __syncthreads();
    }
    if (tid < 4) SM[FEATo + tid] = fmaxf(SM[REDo + tid * 128] + fcb[tid], 0.f);
    __syncthreads();

    // ---- quantum circuit: psi = RX-encoded product state; chi = U psi ----
    if (tid < 16) {
        int j = tid;
        float re = 1.f, im = 0.f;
        #pragma unroll
        for (int w = 0; w < 4; w++) {
            float half = 0.5f * SM[FEATo + w];
            float cc = cosf(half), ss = sinf(half);
            if ((j >> (3 - w)) & 1) {   // amplitude factor -i*sin
                float nr = ss * im, ni = -ss * re;
                re = nr; im = ni;
            } else {                     // amplitude factor cos
                re *= cc; im *= cc;
            }
        }
        SM[PSIo + 2 * j] = re; SM[PSIo + 2 * j + 1] = im;
    }
    __syncthreads();
    if (tid < 16) {
        int r = tid;
        float ar = 0.f, ai = 0.f;
        const float2* U2 = (const float2*)Ug;
        #pragma unroll
        for (int j2 = 0; j2 < 16; j2++) {
            float2 u = U2[r * 16 + j2];
            float pr = SM[PSIo + 2 * j2], pi = SM[PSIo + 2 * j2 + 1];
            ar += u.x * pr - u.y * pi;
            ai += u.x * pi + u.y * pr;
        }
        SM[PVo + r] = ar * ar + ai * ai;
    }
    __syncthreads();
    if (tid < 4) {
        int w = tid, msk = 8 >> w;
        float e = 0.f;
        #pragma unroll
        for (int r = 0; r < 16; r++) {
            float p = SM[PVo + r];
            e += (r & msk) ? -p : p;
        }
        exps[(size_t)bidx * 4 + w] = e;
    }
}

// ---------------------------------------------------------------------------
// Kernel 2: BN batch stats (biased var) in double, folded with gamma/beta and
// the output linear layer into out[b] = sum_w exps[b,w]*A[w] + C.
// stats = {A0,A1,A2,A3,C}
// ---------------------------------------------------------------------------
__global__ __launch_bounds__(256) void bn_stats_kernel(
        const float* __restrict__ exps, const float* __restrict__ gamma,
        const float* __restrict__ beta, const float* __restrict__ ow,
        const float* __restrict__ ob, float* __restrict__ stats, int B) {
    int tid = threadIdx.x;
    double s0 = 0, s1 = 0, s2 = 0, s3 = 0, q0 = 0, q1 = 0, q2 = 0, q3 = 0;
    for (int i = tid; i < B; i += 256) {
        float4 e = reinterpret_cast<const float4*>(exps)[i];
        s0 += e.x; q0 += (double)e.x * e.x;
        s1 += e.y; q1 += (double)e.y * e.y;
        s2 += e.z; q2 += (double)e.z * e.z;
        s3 += e.w; q3 += (double)e.w * e.w;
    }
    __shared__ double red[8][256];
    red[0][tid] = s0; red[1][tid] = s1; red[2][tid] = s2; red[3][tid] = s3;
    red[4][tid] = q0; red[5][tid] = q1; red[6][tid] = q2; red[7][tid] = q3;
    __syncthreads();
    for (int st = 128; st > 0; st >>= 1) {
        if (tid < st)
            for (int k = 0; k < 8; k++) red[k][tid] += red[k][tid + st];
        __syncthreads();
    }
    if (tid == 0) {
        double C = (double)ob[0];
        for (int w = 0; w < 4; w++) {
            double mean = red[w][0] / (double)B;
            double var  = red[4 + w][0] / (double)B - mean * mean;
            double inv  = 1.0 / sqrt(var + 1e-5);
            double scale = (double)gamma[w] * inv;
            stats[w] = (float)(scale * (double)ow[w]);
            C += ((double)beta[w] - mean * scale) * (double)ow[w];
        }
        stats[4] = (float)C;
    }
}

__global__ __launch_bounds__(256) void out_kernel(
        const float* __restrict__ exps, const float* __restrict__ stats,
        float* __restrict__ out, int B) {
    int b = blockIdx.x * 256 + threadIdx.x;
    if (b >= B) return;
    float4 e = reinterpret_cast<const float4*>(exps)[b];
    out[b] = fmaf(e.x, stats[0],
             fmaf(e.y, stats[1],
             fmaf(e.z, stats[2],
             fmaf(e.w, stats[3], stats[4]))));
}

// ---------------------------------------------------------------------------
extern "C" void kernel_launch(void* const* d_in, const int* in_sizes, int n_in,
                              void* d_out, int out_size, void* d_ws, size_t ws_size,
                              hipStream_t stream) {
    const float* x   = (const float*)d_in[0];
    const float* c1w = (const float*)d_in[1];
    const float* c1b = (const float*)d_in[2];
    const float* c2w = (const float*)d_in[3];
    const float* c2b = (const float*)d_in[4];
    const float* fcw = (const float*)d_in[5];
    const float* fcb = (const float*)d_in[6];
    const float* qrx = (const float*)d_in[7];
    const float* qry = (const float*)d_in[8];
    const float* qrz = (const float*)d_in[9];
    const float* rl  = (const float*)d_in[10];
    const float* gmm = (const float*)d_in[11];
    const float* bta = (const float*)d_in[12];
    const float* ow  = (const float*)d_in[13];
    const float* ob  = (const float*)d_in[14];
    float* out = (float*)d_out;
    const int B = in_sizes[0] / 784;
    if (B <= 0) return;

    Ops37 ops;
    build_ops_host(&ops);

    float* ws    = (float*)d_ws;
    float* U     = ws;                      // 512 floats
    float* exps  = ws + 512;                // B*4 floats (16B aligned)
    float* stats = ws + 512 + 4 * (size_t)B;// 5 floats

    build_u_kernel<<<dim3(1), dim3(64), 0, stream>>>(rl, qrx, qry, qrz, U, ops);
    fused_fwd_kernel<<<dim3(B), dim3(128), 0, stream>>>(
        x, c1w, c1b, c2w, c2b, fcw, fcb, U, exps);
    bn_stats_kernel<<<dim3(1), dim3(256), 0, stream>>>(exps, gmm, bta, ow, ob, stats, B);
    out_kernel<<<dim3((B + 255) / 256), dim3(256), 0, stream>>>(exps, stats, out, B);
}

// Round 4
// 191.225 us; speedup vs baseline: 1.0844x; 1.0844x over previous
//
#include <hip/hip_runtime.h>
#include <stdint.h>
#include <math.h>

#define NOPS 37

struct Ops37 {
    int type[NOPS];  // 0 rx, 1 ry, 2 rz, 3 cnot, 4 H, 5 SX
    int a[NOPS];     // wire (rot/H/SX) or control (cnot)
    int b[NOPS];     // target (cnot), else -1
};

// ---------------------------------------------------------------------------
// Host-side exact replication of np.random.default_rng(42) for _random_ops().
// VERIFIED PASSING (round 3): SeedSequence mix uses SUBTRACTION
// (x*MIX_MULT_L - y*MIX_MULT_R), Lemire-32 for all bounded draws incl. the
// _shuffle_int tail of choice(replace=False); pcg64_next32 low-word-first.
// DO NOT TOUCH.
// ---------------------------------------------------------------------------
static void build_ops_host(Ops37* ops) {
    uint32_t pool[4];
    uint32_t hc = 0x43b0d7e5u;  // INIT_A
    auto hmix = [&hc](uint32_t value) -> uint32_t {
        value ^= hc;
        hc *= 0x931e8875u;      // MULT_A
        value *= hc;
        value ^= value >> 16;
        return value;
    };
    auto mixf = [](uint32_t x, uint32_t y) -> uint32_t {
        uint32_t r = (x * 0xca01f9ddu) - (y * 0x4973f715u);  // SUBTRACTION
        r ^= r >> 16;
        return r;
    };
    pool[0] = hmix(42u);
    for (int i = 1; i < 4; i++) pool[i] = hmix(0u);
    for (int s = 0; s < 4; s++)
        for (int d = 0; d < 4; d++)
            if (s != d) pool[d] = mixf(pool[d], hmix(pool[s]));

    uint32_t st[8];
    {
        uint32_t hcb = 0x8b51f9ddu;  // INIT_B
        for (int i = 0; i < 8; i++) {
            uint32_t dv = pool[i & 3];
            dv ^= hcb;
            hcb *= 0x58f38dedu;      // MULT_B
            dv *= hcb;
            dv ^= dv >> 16;
            st[i] = dv;
        }
    }
    typedef __uint128_t u128;
    const uint64_t v0 = (uint64_t)st[0] | ((uint64_t)st[1] << 32);
    const uint64_t v1 = (uint64_t)st[2] | ((uint64_t)st[3] << 32);
    const uint64_t v2 = (uint64_t)st[4] | ((uint64_t)st[5] << 32);
    const uint64_t v3 = (uint64_t)st[6] | ((uint64_t)st[7] << 32);
    const u128 initstate = (((u128)v0) << 64) | v1;
    const u128 initseq   = (((u128)v2) << 64) | v3;
    const u128 MULT = (((u128)0x2360ed051fc65da4ULL) << 64) | 0x4385df649fccf645ULL;

    u128 state = 0;
    const u128 inc = (initseq << 1) | 1;
    state = state * MULT + inc;
    state += initstate;
    state = state * MULT + inc;

    bool has32 = false;
    uint32_t cached = 0;
    auto next64 = [&]() -> uint64_t {
        state = state * MULT + inc;
        uint64_t hi = (uint64_t)(state >> 64);
        uint64_t lo = (uint64_t)state;
        unsigned rot = (unsigned)(state >> 122) & 63u;
        uint64_t v = hi ^ lo;
        return (v >> rot) | (v << ((64u - rot) & 63u));
    };
    auto next32 = [&]() -> uint32_t {
        if (has32) { has32 = false; return cached; }
        uint64_t n = next64();
        has32 = true;
        cached = (uint32_t)(n >> 32);
        return (uint32_t)n;
    };
    auto lem = [&](uint32_t rng) -> uint32_t {
        const uint32_t rng_excl = rng + 1u;
        uint64_t m = (uint64_t)next32() * (uint64_t)rng_excl;
        uint32_t leftover = (uint32_t)m;
        if (leftover < rng_excl) {
            const uint32_t threshold = (0xFFFFFFFFu - rng) % rng_excl;
            while (leftover < threshold) {
                m = (uint64_t)next32() * (uint64_t)rng_excl;
                leftover = (uint32_t)m;
            }
        }
        return (uint32_t)(m >> 32);
    };

    for (int k = 0; k < 30; k++) {
        uint32_t g = lem(3);
        if (g == 3u) {
            uint32_t i0 = lem(2);
            uint32_t vv = lem(3);
            uint32_t i1 = (vv == i0) ? 3u : vv;
            uint32_t j = lem(1);
            if (j == 0u) { uint32_t t = i0; i0 = i1; i1 = t; }
            ops->type[k] = 3; ops->a[k] = (int)i0; ops->b[k] = (int)i1;
        } else {
            uint32_t w = lem(3);
            ops->type[k] = (int)g; ops->a[k] = (int)w; ops->b[k] = -1;
        }
    }
    ops->type[30] = 0; ops->a[30] = 0; ops->b[30] = -1;
    ops->type[31] = 1; ops->a[31] = 1; ops->b[31] = -1;
    ops->type[32] = 2; ops->a[32] = 2; ops->b[32] = -1;
    ops->type[33] = 3; ops->a[33] = 0; ops->b[33] = 3;
    ops->type[34] = 4; ops->a[34] = 3; ops->b[34] = -1;
    ops->type[35] = 5; ops->a[35] = 2; ops->b[35] = -1;
    ops->type[36] = 3; ops->a[36] = 3; ops->b[36] = 0;
}

// ---------------------------------------------------------------------------
// Kernel 0: build the fixed 16x16 unitary U (post-encoding circuit).
// ---------------------------------------------------------------------------
__global__ __launch_bounds__(64) void build_u_kernel(
        const float* __restrict__ rl, const float* __restrict__ qrx,
        const float* __restrict__ qry, const float* __restrict__ qrz,
        float* __restrict__ Uout, Ops37 ops) {
    int j = threadIdx.x;
    if (j >= 16) return;
    double cr[16], ci[16];
    for (int i = 0; i < 16; i++) { cr[i] = (i == j) ? 1.0 : 0.0; ci[i] = 0.0; }
    for (int k = 0; k < NOPS; k++) {
        int t = ops.type[k];
        if (t == 3) {
            int mc = 8 >> ops.a[k], mt = 8 >> ops.b[k];
            for (int i = 0; i < 16; i++) {
                if ((i & mc) && !(i & mt)) {
                    int i2 = i | mt;
                    double tr = cr[i], ti = ci[i];
                    cr[i] = cr[i2]; ci[i] = ci[i2];
                    cr[i2] = tr;    ci[i2] = ti;
                }
            }
        } else {
            double g00r, g00i, g01r, g01i, g10r, g10i, g11r, g11i;
            if (t == 4) {
                const double r = 0.70710678118654752440;
                g00r = r; g00i = 0; g01r = r;  g01i = 0;
                g10r = r; g10i = 0; g11r = -r; g11i = 0;
            } else if (t == 5) {
                g00r = 0.5; g00i = 0.5;  g01r = 0.5; g01i = -0.5;
                g10r = 0.5; g10i = -0.5; g11r = 0.5; g11i = 0.5;
            } else {
                float th = (k < 30) ? rl[k]
                         : (k == 30 ? qrx[0] : (k == 31 ? qry[0] : qrz[0]));
                double c = cos(0.5 * (double)th), s = sin(0.5 * (double)th);
                if (t == 0) {
                    g00r = c; g00i = 0;  g01r = 0; g01i = -s;
                    g10r = 0; g10i = -s; g11r = c; g11i = 0;
                } else if (t == 1) {
                    g00r = c; g00i = 0; g01r = -s; g01i = 0;
                    g10r = s; g10i = 0; g11r = c;  g11i = 0;
                } else {
                    g00r = c; g00i = -s; g01r = 0; g01i = 0;
                    g10r = 0; g10i = 0;  g11r = c; g11i = s;
                }
            }
            int m = 8 >> ops.a[k];
            for (int i = 0; i < 16; i++) {
                if (!(i & m)) {
                    int i2 = i | m;
                    double ar = cr[i], ai = ci[i], br = cr[i2], bi = ci[i2];
                    cr[i]  = g00r * ar - g00i * ai + g01r * br - g01i * bi;
                    ci[i]  = g00r * ai + g00i * ar + g01r * bi + g01i * br;
                    cr[i2] = g10r * ar - g10i * ai + g11r * br - g11i * bi;
                    ci[i2] = g10r * ai + g10i * ar + g11r * bi + g11i * br;
                }
            }
        }
    }
    for (int i = 0; i < 16; i++) {
        Uout[2 * (i * 16 + j)]     = (float)cr[i];
        Uout[2 * (i * 16 + j) + 1] = (float)ci[i];
    }
}

// ---------------------------------------------------------------------------
// Kernel 1: fused per-sample forward. One block (128 threads) per sample.
// Round-4 changes vs round 3 (math identical):
//  - weights read directly from global (L1/L2-hot, 4.9 KB total) — LDS
//    drops 20.5 KB -> 14.1 KB => 11 blocks/CU (was 7), and the 10-way
//    W2 LDS bank conflict is gone.
//  - conv1 tiles 2 adjacent pooled outputs/thread (shared 4x6 patch).
//  - fc reduction: wave shfl_down + 8-float LDS handoff (2 barriers, was 8).
// LDS (floats): XP 30x30 [0,900) reused as h2[784]; H1 8x16x20 [900,3460)
// (rows padded to 20 to break the 128B stride); RED[8] FEAT[4] PSI[32] PV[16].
// ---------------------------------------------------------------------------
#define XPo   0
#define H2o   0
#define H1o   900
#define REDo  3460
#define FEATo 3468
#define PSIo  3472
#define PVo   3504
#define SMSZ  3520

__global__ __launch_bounds__(128) void fused_fwd_kernel(
        const float* __restrict__ x,
        const float* __restrict__ c1w, const float* __restrict__ c1b,
        const float* __restrict__ c2w, const float* __restrict__ c2b,
        const float* __restrict__ fcw, const float* __restrict__ fcb,
        const float* __restrict__ Ug, float* __restrict__ exps) {
    __shared__ __align__(16) float SM[SMSZ];
    const int tid = threadIdx.x;
    const int bidx = blockIdx.x;

    // ---- stage x (zero-padded 30x30), zero h1 (incl. borders) ----
    {
        const float* xb = x + (size_t)bidx * 784;
        for (int i = tid; i < 900; i += 128) {
            int r = i / 30, c = i - r * 30;
            float v = 0.f;
            if (r >= 1 && r <= 28 && c >= 1 && c <= 28) v = xb[(r - 1) * 28 + (c - 1)];
            SM[XPo + i] = v;
        }
    }
    for (int i = tid; i < 2560; i += 128) SM[H1o + i] = 0.f;
    __syncthreads();

    // ---- conv1 + relu + pool: 2 adjacent pooled outputs per work item ----
    // item w in [0,784): c = w/98, py = (w%98)/7, pxp = w%7 -> px {2pxp, 2pxp+1}
    for (int w = tid; w < 784; w += 128) {
        int c   = w / 98;
        int rem = w - c * 98;
        int py  = rem / 7, pxp = rem - py * 7;
        float P[4][6];
        #pragma unroll
        for (int r = 0; r < 4; r++) {
            const float2 a  = *(const float2*)&SM[XPo + (2 * py + r) * 30 + 4 * pxp];
            const float2 b_ = *(const float2*)&SM[XPo + (2 * py + r) * 30 + 4 * pxp + 2];
            const float2 c_ = *(const float2*)&SM[XPo + (2 * py + r) * 30 + 4 * pxp + 4];
            P[r][0] = a.x; P[r][1] = a.y; P[r][2] = b_.x;
            P[r][3] = b_.y; P[r][4] = c_.x; P[r][5] = c_.y;
        }
        float wv[9];
        #pragma unroll
        for (int t = 0; t < 9; t++) wv[t] = c1w[c * 9 + t];
        const float bb = c1b[c];
        #pragma unroll
        for (int half = 0; half < 2; half++) {   // px = 2*pxp + half, cols off 2*half
            float m = -3.4e38f;
            #pragma unroll
            for (int dy = 0; dy < 2; dy++)
                #pragma unroll
                for (int dx = 0; dx < 2; dx++) {
                    float acc = 0.f;
                    #pragma unroll
                    for (int ky = 0; ky < 3; ky++)
                        #pragma unroll
                        for (int kx = 0; kx < 3; kx++)
                            acc = fmaf(P[dy + ky][2 * half + dx + kx], wv[ky * 3 + kx], acc);
                    m = fmaxf(m, acc);
                }
            SM[H1o + c * 320 + (py + 1) * 20 + (2 * pxp + half + 1)] = fmaxf(m + bb, 0.f);
        }
    }
    __syncthreads();

    // ---- conv2 + relu + pool: thread = (c2,py) row, 7 pooled outputs ----
    if (tid < 112) {
        int c2 = tid / 7, py = tid - (tid / 7) * 7;
        float acc[7][4];
        #pragma unroll
        for (int px = 0; px < 7; px++)
            #pragma unroll
            for (int s = 0; s < 4; s++) acc[px][s] = 0.f;
        for (int c1 = 0; c1 < 8; c1++) {
            float R[4][16];
            #pragma unroll
            for (int r = 0; r < 4; r++) {
                #pragma unroll
                for (int q = 0; q < 4; q++) {
                    const float4 v = *(const float4*)&SM[H1o + c1 * 320 + (2 * py + r) * 20 + 4 * q];
                    R[r][4 * q + 0] = v.x; R[r][4 * q + 1] = v.y;
                    R[r][4 * q + 2] = v.z; R[r][4 * q + 3] = v.w;
                }
            }
            float w[9];
            #pragma unroll
            for (int t = 0; t < 9; t++) w[t] = c2w[(c2 * 8 + c1) * 9 + t];
            #pragma unroll
            for (int px = 0; px < 7; px++)
                #pragma unroll
                for (int dy = 0; dy < 2; dy++)
                    #pragma unroll
                    for (int dx = 0; dx < 2; dx++) {
                        float a = acc[px][dy * 2 + dx];
                        #pragma unroll
                        for (int ky = 0; ky < 3; ky++)
                            #pragma unroll
                            for (int kx = 0; kx < 3; kx++)
                                a = fmaf(R[dy + ky][2 * px + dx + kx], w[ky * 3 + kx], a);
                        acc[px][dy * 2 + dx] = a;
                    }
        }
        const float bb = c2b[c2];
        #pragma unroll
        for (int px = 0; px < 7; px++) {
            float m = fmaxf(fmaxf(acc[px][0], acc[px][1]), fmaxf(acc[px][2], acc[px][3]));
            SM[H2o + c2 * 49 + py * 7 + px] = fmaxf(m + bb, 0.f);
        }
    }
    __syncthreads();

    // ---- fc rows 0..3 (only feat[:, :4] is ever used): shfl reduction ----
    {
        float a0 = 0.f, a1 = 0.f, a2 = 0.f, a3 = 0.f;
        for (int j = tid; j < 784; j += 128) {
            float h = SM[H2o + j];
            a0 = fmaf(h, fcw[j],        a0);
            a1 = fmaf(h, fcw[784 + j],  a1);
            a2 = fmaf(h, fcw[1568 + j], a2);
            a3 = fmaf(h, fcw[2352 + j], a3);
        }
        #pragma unroll
        for (int off = 32; off > 0; off >>= 1) {
            a0 += __shfl_down(a0, off);
            a1 += __shfl_down(a1, off);
            a2 += __shfl_down(a2, off);
            a3 += __shfl_down(a3, off);
        }
        if ((tid & 63) == 0) {
            int wid = tid >> 6;
            SM[REDo + wid * 4 + 0] = a0;
            SM[REDo + wid * 4 + 1] = a1;
            SM[REDo + wid * 4 + 2] = a2;
            SM[REDo + wid * 4 + 3] = a3;
        }
    }
    __syncthreads();
    if (tid < 4)
        SM[FEATo + tid] = fmaxf(SM[REDo + tid] + SM[REDo + 4 + tid] + fcb[tid], 0.f);
    __syncthreads();

    // ---- quantum circuit: psi = RX-encoded product state; chi = U psi ----
    if (tid < 16) {
        int j = tid;
        float re = 1.f, im = 0.f;
        #pragma unroll
        for (int w = 0; w < 4; w++) {
            float half = 0.5f * SM[FEATo + w];
            float cc = cosf(half), ss = sinf(half);
            if ((j >> (3 - w)) & 1) {
                float nr = ss * im, ni = -ss * re;
                re = nr; im = ni;
            } else {
                re *= cc; im *= cc;
            }
        }
        SM[PSIo + 2 * j] = re; SM[PSIo + 2 * j + 1] = im;
    }
    __syncthreads();
    if (tid < 16) {
        int r = tid;
        float ar = 0.f, ai = 0.f;
        const float2* U2 = (const float2*)Ug;
        #pragma unroll
        for (int j2 = 0; j2 < 16; j2++) {
            float2 u = U2[r * 16 + j2];
            float pr = SM[PSIo + 2 * j2], pi = SM[PSIo + 2 * j2 + 1];
            ar += u.x * pr - u.y * pi;
            ai += u.x * pi + u.y * pr;
        }
        SM[PVo + r] = ar * ar + ai * ai;
    }
    __syncthreads();
    if (tid < 4) {
        int w = tid, msk = 8 >> w;
        float e = 0.f;
        #pragma unroll
        for (int r = 0; r < 16; r++) {
            float p = SM[PVo + r];
            e += (r & msk) ? -p : p;
        }
        exps[(size_t)bidx * 4 + w] = e;
    }
}

// ---------------------------------------------------------------------------
// Kernel 2: BN batch stats (biased var) folded with gamma/beta and the output
// linear layer into out[b] = sum_w exps[b,w]*A[w] + C.  stats = {A0..A3, C}
// ---------------------------------------------------------------------------
__global__ __launch_bounds__(256) void bn_stats_kernel(
        const float* __restrict__ exps, const float* __restrict__ gamma,
        const float* __restrict__ beta, const float* __restrict__ ow,
        const float* __restrict__ ob, float* __restrict__ stats, int B) {
    int tid = threadIdx.x;
    double s0 = 0, s1 = 0, s2 = 0, s3 = 0, q0 = 0, q1 = 0, q2 = 0, q3 = 0;
    for (int i = tid; i < B; i += 256) {
        float4 e = reinterpret_cast<const float4*>(exps)[i];
        s0 += e.x; q0 += (double)e.x * e.x;
        s1 += e.y; q1 += (double)e.y * e.y;
        s2 += e.z; q2 += (double)e.z * e.z;
        s3 += e.w; q3 += (double)e.w * e.w;
    }
    __shared__ double red[8][256];
    red[0][tid] = s0; red[1][tid] = s1; red[2][tid] = s2; red[3][tid] = s3;
    red[4][tid] = q0; red[5][tid] = q1; red[6][tid] = q2; red[7][tid] = q3;
    __syncthreads();
    for (int st = 128; st > 0; st >>= 1) {
        if (tid < st)
            for (int k = 0; k < 8; k++) red[k][tid] += red[k][tid + st];
        __syncthreads();
    }
    if (tid == 0) {
        double C = (double)ob[0];
        for (int w = 0; w < 4; w++) {
            double mean = red[w][0] / (double)B;
            double var  = red[4 + w][0] / (double)B - mean * mean;
            double inv  = 1.0 / sqrt(var + 1e-5);
            double scale = (double)gamma[w] * inv;
            stats[w] = (float)(scale * (double)ow[w]);
            C += ((double)beta[w] - mean * scale) * (double)ow[w];
        }
        stats[4] = (float)C;
    }
}

__global__ __launch_bounds__(256) void out_kernel(
        const float* __restrict__ exps, const float* __restrict__ stats,
        float* __restrict__ out, int B) {
    int b = blockIdx.x * 256 + threadIdx.x;
    if (b >= B) return;
    float4 e = reinterpret_cast<const float4*>(exps)[b];
    out[b] = fmaf(e.x, stats[0],
             fmaf(e.y, stats[1],
             fmaf(e.z, stats[2],
             fmaf(e.w, stats[3], stats[4]))));
}

// ---------------------------------------------------------------------------
extern "C" void kernel_launch(void* const* d_in, const int* in_sizes, int n_in,
                              void* d_out, int out_size, void* d_ws, size_t ws_size,
                              hipStream_t stream) {
    const float* x   = (const float*)d_in[0];
    const float* c1w = (const float*)d_in[1];
    const float* c1b = (const float*)d_in[2];
    const float* c2w = (const float*)d_in[3];
    const float* c2b = (const float*)d_in[4];
    const float* fcw = (const float*)d_in[5];
    const float* fcb = (const float*)d_in[6];
    const float* qrx = (const float*)d_in[7];
    const float* qry = (const float*)d_in[8];
    const float* qrz = (const float*)d_in[9];
    const float* rl  = (const float*)d_in[10];
    const float* gmm = (const float*)d_in[11];
    const float* bta = (const float*)d_in[12];
    const float* ow  = (const float*)d_in[13];
    const float* ob  = (const float*)d_in[14];
    float* out = (float*)d_out;
    const int B = in_sizes[0] / 784;
    if (B <= 0) return;

    Ops37 ops;
    build_ops_host(&ops);

    float* ws    = (float*)d_ws;
    float* U     = ws;                      // 512 floats
    float* exps  = ws + 512;                // B*4 floats (16B aligned)
    float* stats = ws + 512 + 4 * (size_t)B;// 5 floats

    build_u_kernel<<<dim3(1), dim3(64), 0, stream>>>(rl, qrx, qry, qrz, U, ops);
    fused_fwd_kernel<<<dim3(B), dim3(128), 0, stream>>>(
        x, c1w, c1b, c2w, c2b, fcw, fcb, U, exps);
    bn_stats_kernel<<<dim3(1), dim3(256), 0, stream>>>(exps, gmm, bta, ow, ob, stats, B);
    out_kernel<<<dim3((B + 255) / 256), dim3(256), 0, stream>>>(exps, stats, out, B);
}

// Round 5
// 185.916 us; speedup vs baseline: 1.1154x; 1.0286x over previous
//
#include <hip/hip_runtime.h>
#include <stdint.h>
#include <math.h>

#define NOPS 37

struct Ops37 {
    int type[NOPS];  // 0 rx, 1 ry, 2 rz, 3 cnot, 4 H, 5 SX
    int a[NOPS];     // wire (rot/H/SX) or control (cnot)
    int b[NOPS];     // target (cnot), else -1
};

// ---------------------------------------------------------------------------
// Host-side exact replication of np.random.default_rng(42) for _random_ops().
// VERIFIED PASSING (round 3): SeedSequence mix uses SUBTRACTION
// (x*MIX_MULT_L - y*MIX_MULT_R), Lemire-32 for all bounded draws incl. the
// _shuffle_int tail of choice(replace=False); pcg64_next32 low-word-first.
// DO NOT TOUCH.
// ---------------------------------------------------------------------------
static void build_ops_host(Ops37* ops) {
    uint32_t pool[4];
    uint32_t hc = 0x43b0d7e5u;  // INIT_A
    auto hmix = [&hc](uint32_t value) -> uint32_t {
        value ^= hc;
        hc *= 0x931e8875u;      // MULT_A
        value *= hc;
        value ^= value >> 16;
        return value;
    };
    auto mixf = [](uint32_t x, uint32_t y) -> uint32_t {
        uint32_t r = (x * 0xca01f9ddu) - (y * 0x4973f715u);  // SUBTRACTION
        r ^= r >> 16;
        return r;
    };
    pool[0] = hmix(42u);
    for (int i = 1; i < 4; i++) pool[i] = hmix(0u);
    for (int s = 0; s < 4; s++)
        for (int d = 0; d < 4; d++)
            if (s != d) pool[d] = mixf(pool[d], hmix(pool[s]));

    uint32_t st[8];
    {
        uint32_t hcb = 0x8b51f9ddu;  // INIT_B
        for (int i = 0; i < 8; i++) {
            uint32_t dv = pool[i & 3];
            dv ^= hcb;
            hcb *= 0x58f38dedu;      // MULT_B
            dv *= hcb;
            dv ^= dv >> 16;
            st[i] = dv;
        }
    }
    typedef __uint128_t u128;
    const uint64_t v0 = (uint64_t)st[0] | ((uint64_t)st[1] << 32);
    const uint64_t v1 = (uint64_t)st[2] | ((uint64_t)st[3] << 32);
    const uint64_t v2 = (uint64_t)st[4] | ((uint64_t)st[5] << 32);
    const uint64_t v3 = (uint64_t)st[6] | ((uint64_t)st[7] << 32);
    const u128 initstate = (((u128)v0) << 64) | v1;
    const u128 initseq   = (((u128)v2) << 64) | v3;
    const u128 MULT = (((u128)0x2360ed051fc65da4ULL) << 64) | 0x4385df649fccf645ULL;

    u128 state = 0;
    const u128 inc = (initseq << 1) | 1;
    state = state * MULT + inc;
    state += initstate;
    state = state * MULT + inc;

    bool has32 = false;
    uint32_t cached = 0;
    auto next64 = [&]() -> uint64_t {
        state = state * MULT + inc;
        uint64_t hi = (uint64_t)(state >> 64);
        uint64_t lo = (uint64_t)state;
        unsigned rot = (unsigned)(state >> 122) & 63u;
        uint64_t v = hi ^ lo;
        return (v >> rot) | (v << ((64u - rot) & 63u));
    };
    auto next32 = [&]() -> uint32_t {
        if (has32) { has32 = false; return cached; }
        uint64_t n = next64();
        has32 = true;
        cached = (uint32_t)(n >> 32);
        return (uint32_t)n;
    };
    auto lem = [&](uint32_t rng) -> uint32_t {
        const uint32_t rng_excl = rng + 1u;
        uint64_t m = (uint64_t)next32() * (uint64_t)rng_excl;
        uint32_t leftover = (uint32_t)m;
        if (leftover < rng_excl) {
            const uint32_t threshold = (0xFFFFFFFFu - rng) % rng_excl;
            while (leftover < threshold) {
                m = (uint64_t)next32() * (uint64_t)rng_excl;
                leftover = (uint32_t)m;
            }
        }
        return (uint32_t)(m >> 32);
    };

    for (int k = 0; k < 30; k++) {
        uint32_t g = lem(3);
        if (g == 3u) {
            uint32_t i0 = lem(2);
            uint32_t vv = lem(3);
            uint32_t i1 = (vv == i0) ? 3u : vv;
            uint32_t j = lem(1);
            if (j == 0u) { uint32_t t = i0; i0 = i1; i1 = t; }
            ops->type[k] = 3; ops->a[k] = (int)i0; ops->b[k] = (int)i1;
        } else {
            uint32_t w = lem(3);
            ops->type[k] = (int)g; ops->a[k] = (int)w; ops->b[k] = -1;
        }
    }
    ops->type[30] = 0; ops->a[30] = 0; ops->b[30] = -1;
    ops->type[31] = 1; ops->a[31] = 1; ops->b[31] = -1;
    ops->type[32] = 2; ops->a[32] = 2; ops->b[32] = -1;
    ops->type[33] = 3; ops->a[33] = 0; ops->b[33] = 3;
    ops->type[34] = 4; ops->a[34] = 3; ops->b[34] = -1;
    ops->type[35] = 5; ops->a[35] = 2; ops->b[35] = -1;
    ops->type[36] = 3; ops->a[36] = 3; ops->b[36] = 0;
}

// ---------------------------------------------------------------------------
// Kernel 0: build the fixed 16x16 unitary U (post-encoding circuit).
// ---------------------------------------------------------------------------
__global__ __launch_bounds__(64) void build_u_kernel(
        const float* __restrict__ rl, const float* __restrict__ qrx,
        const float* __restrict__ qry, const float* __restrict__ qrz,
        float* __restrict__ Uout, Ops37 ops) {
    int j = threadIdx.x;
    if (j >= 16) return;
    double cr[16], ci[16];
    for (int i = 0; i < 16; i++) { cr[i] = (i == j) ? 1.0 : 0.0; ci[i] = 0.0; }
    for (int k = 0; k < NOPS; k++) {
        int t = ops.type[k];
        if (t == 3) {
            int mc = 8 >> ops.a[k], mt = 8 >> ops.b[k];
            for (int i = 0; i < 16; i++) {
                if ((i & mc) && !(i & mt)) {
                    int i2 = i | mt;
                    double tr = cr[i], ti = ci[i];
                    cr[i] = cr[i2]; ci[i] = ci[i2];
                    cr[i2] = tr;    ci[i2] = ti;
                }
            }
        } else {
            double g00r, g00i, g01r, g01i, g10r, g10i, g11r, g11i;
            if (t == 4) {
                const double r = 0.70710678118654752440;
                g00r = r; g00i = 0; g01r = r;  g01i = 0;
                g10r = r; g10i = 0; g11r = -r; g11i = 0;
            } else if (t == 5) {
                g00r = 0.5; g00i = 0.5;  g01r = 0.5; g01i = -0.5;
                g10r = 0.5; g10i = -0.5; g11r = 0.5; g11i = 0.5;
            } else {
                float th = (k < 30) ? rl[k]
                         : (k == 30 ? qrx[0] : (k == 31 ? qry[0] : qrz[0]));
                double c = cos(0.5 * (double)th), s = sin(0.5 * (double)th);
                if (t == 0) {
                    g00r = c; g00i = 0;  g01r = 0; g01i = -s;
                    g10r = 0; g10i = -s; g11r = c; g11i = 0;
                } else if (t == 1) {
                    g00r = c; g00i = 0; g01r = -s; g01i = 0;
                    g10r = s; g10i = 0; g11r = c;  g11i = 0;
                } else {
                    g00r = c; g00i = -s; g01r = 0; g01i = 0;
                    g10r = 0; g10i = 0;  g11r = c; g11i = s;
                }
            }
            int m = 8 >> ops.a[k];
            for (int i = 0; i < 16; i++) {
                if (!(i & m)) {
                    int i2 = i | m;
                    double ar = cr[i], ai = ci[i], br = cr[i2], bi = ci[i2];
                    cr[i]  = g00r * ar - g00i * ai + g01r * br - g01i * bi;
                    ci[i]  = g00r * ai + g00i * ar + g01r * bi + g01i * br;
                    cr[i2] = g10r * ar - g10i * ai + g11r * br - g11i * bi;
                    ci[i2] = g10r * ai + g10i * ar + g11r * bi + g11i * br;
                }
            }
        }
    }
    for (int i = 0; i < 16; i++) {
        Uout[2 * (i * 16 + j)]     = (float)cr[i];
        Uout[2 * (i * 16 + j) + 1] = (float)ci[i];
    }
}

// ---------------------------------------------------------------------------
// Kernel 1: fused per-sample forward. One block (128 threads) per sample.
// Round-5 changes vs round 4 (math identical; bank-conflict surgery):
//  - XP row stride 30 -> 34 (= 2 mod 32): conv1 read banks spread; worst 2-way.
//  - conv1 thread map: c = tid&7, pos = tid>>3 — the 8 channel-lanes of a
//    position broadcast the same XP address (free); weights live in 10 regs,
//    loaded once (was 6x per thread).
//  - H1 channel stride 320 -> 324 (320 = 0 mod 32 would make the new write
//    pattern 8-way; 324 gives bank 4*c — conflict-free writes, conv2 reads
//    stay broadcast/2-way).
// LDS (floats): XP 30x34 [0,1020) reused as h2[784]; H1 8x324 [1020,3612);
// RED[8] FEAT[4] PSI[32] PV[16]. 14.7 KB -> 11 blocks/CU.
// ---------------------------------------------------------------------------
#define XPo   0
#define H2o   0
#define H1o   1020
#define REDo  3612
#define FEATo 3620
#define PSIo  3624
#define PVo   3656
#define SMSZ  3680

__global__ __launch_bounds__(128) void fused_fwd_kernel(
        const float* __restrict__ x,
        const float* __restrict__ c1w, const float* __restrict__ c1b,
        const float* __restrict__ c2w, const float* __restrict__ c2b,
        const float* __restrict__ fcw, const float* __restrict__ fcb,
        const float* __restrict__ Ug, float* __restrict__ exps) {
    __shared__ __align__(16) float SM[SMSZ];
    const int tid = threadIdx.x;
    const int bidx = blockIdx.x;

    // ---- stage x (zero-padded 30x34), zero h1 (incl. borders) ----
    {
        const float* xb = x + (size_t)bidx * 784;
        for (int i = tid; i < 1020; i += 128) {
            int r = i / 34, c = i - r * 34;
            float v = 0.f;
            if (r >= 1 && r <= 28 && c >= 1 && c <= 28) v = xb[(r - 1) * 28 + (c - 1)];
            SM[XPo + i] = v;
        }
    }
    for (int i = tid; i < 2592; i += 128) SM[H1o + i] = 0.f;
    __syncthreads();

    // ---- conv1 + relu + pool: c fixed per thread; 2 pooled outputs/item ----
    {
        const int c    = tid & 7;
        const int pos0 = tid >> 3;   // 0..15; pos = py*7 + pxp, pos < 98
        float wv[9];
        #pragma unroll
        for (int t = 0; t < 9; t++) wv[t] = c1w[c * 9 + t];
        const float bb = c1b[c];
        for (int pos = pos0; pos < 98; pos += 16) {
            int py = pos / 7, pxp = pos - py * 7;
            float P[4][6];
            #pragma unroll
            for (int r = 0; r < 4; r++) {
                const float2 a  = *(const float2*)&SM[XPo + (2 * py + r) * 34 + 4 * pxp];
                const float2 b_ = *(const float2*)&SM[XPo + (2 * py + r) * 34 + 4 * pxp + 2];
                const float2 c_ = *(const float2*)&SM[XPo + (2 * py + r) * 34 + 4 * pxp + 4];
                P[r][0] = a.x; P[r][1] = a.y; P[r][2] = b_.x;
                P[r][3] = b_.y; P[r][4] = c_.x; P[r][5] = c_.y;
            }
            #pragma unroll
            for (int half = 0; half < 2; half++) {  // px = 2*pxp + half
                float m = -3.4e38f;
                #pragma unroll
                for (int dy = 0; dy < 2; dy++)
                    #pragma unroll
                    for (int dx = 0; dx < 2; dx++) {
                        float acc = 0.f;
                        #pragma unroll
                        for (int ky = 0; ky < 3; ky++)
                            #pragma unroll
                            for (int kx = 0; kx < 3; kx++)
                                acc = fmaf(P[dy + ky][2 * half + dx + kx], wv[ky * 3 + kx], acc);
                        m = fmaxf(m, acc);
                    }
                SM[H1o + c * 324 + (py + 1) * 20 + (2 * pxp + half + 1)] = fmaxf(m + bb, 0.f);
            }
        }
    }
    __syncthreads();

    // ---- conv2 + relu + pool: thread = (c2,py) row, 7 pooled outputs ----
    if (tid < 112) {
        int c2 = tid / 7, py = tid - (tid / 7) * 7;
        float acc[7][4];
        #pragma unroll
        for (int px = 0; px < 7; px++)
            #pragma unroll
            for (int s = 0; s < 4; s++) acc[px][s] = 0.f;
        for (int c1 = 0; c1 < 8; c1++) {
            float R[4][16];
            #pragma unroll
            for (int r = 0; r < 4; r++) {
                #pragma unroll
                for (int q = 0; q < 4; q++) {
                    const float4 v = *(const float4*)&SM[H1o + c1 * 324 + (2 * py + r) * 20 + 4 * q];
                    R[r][4 * q + 0] = v.x; R[r][4 * q + 1] = v.y;
                    R[r][4 * q + 2] = v.z; R[r][4 * q + 3] = v.w;
                }
            }
            float w[9];
            #pragma unroll
            for (int t = 0; t < 9; t++) w[t] = c2w[(c2 * 8 + c1) * 9 + t];
            #pragma unroll
            for (int px = 0; px < 7; px++)
                #pragma unroll
                for (int dy = 0; dy < 2; dy++)
                    #pragma unroll
                    for (int dx = 0; dx < 2; dx++) {
                        float a = acc[px][dy * 2 + dx];
                        #pragma unroll
                        for (int ky = 0; ky < 3; ky++)
                            #pragma unroll
                            for (int kx = 0; kx < 3; kx++)
                                a = fmaf(R[dy + ky][2 * px + dx + kx], w[ky * 3 + kx], a);
                        acc[px][dy * 2 + dx] = a;
                    }
        }
        const float bb = c2b[c2];
        #pragma unroll
        for (int px = 0; px < 7; px++) {
            float m = fmaxf(fmaxf(acc[px][0], acc[px][1]), fmaxf(acc[px][2], acc[px][3]));
            SM[H2o + c2 * 49 + py * 7 + px] = fmaxf(m + bb, 0.f);
        }
    }
    __syncthreads();

    // ---- fc rows 0..3 (only feat[:, :4] is ever used): shfl reduction ----
    {
        float a0 = 0.f, a1 = 0.f, a2 = 0.f, a3 = 0.f;
        for (int j = tid; j < 784; j += 128) {
            float h = SM[H2o + j];
            a0 = fmaf(h, fcw[j],        a0);
            a1 = fmaf(h, fcw[784 + j],  a1);
            a2 = fmaf(h, fcw[1568 + j], a2);
            a3 = fmaf(h, fcw[2352 + j], a3);
        }
        #pragma unroll
        for (int off = 32; off > 0; off >>= 1) {
            a0 += __shfl_down(a0, off);
            a1 += __shfl_down(a1, off);
            a2 += __shfl_down(a2, off);
            a3 += __shfl_down(a3, off);
        }
        if ((tid & 63) == 0) {
            int wid = tid >> 6;
            SM[REDo + wid * 4 + 0] = a0;
            SM[REDo + wid * 4 + 1] = a1;
            SM[REDo + wid * 4 + 2] = a2;
            SM[REDo + wid * 4 + 3] = a3;
        }
    }
    __syncthreads();
    if (tid < 4)
        SM[FEATo + tid] = fmaxf(SM[REDo + tid] + SM[REDo + 4 + tid] + fcb[tid], 0.f);
    __syncthreads();

    // ---- quantum circuit: psi = RX-encoded product state; chi = U psi ----
    if (tid < 16) {
        int j = tid;
        float re = 1.f, im = 0.f;
        #pragma unroll
        for (int w = 0; w < 4; w++) {
            float half = 0.5f * SM[FEATo + w];
            float cc = cosf(half), ss = sinf(half);
            if ((j >> (3 - w)) & 1) {
                float nr = ss * im, ni = -ss * re;
                re = nr; im = ni;
            } else {
                re *= cc; im *= cc;
            }
        }
        SM[PSIo + 2 * j] = re; SM[PSIo + 2 * j + 1] = im;
    }
    __syncthreads();
    if (tid < 16) {
        int r = tid;
        float ar = 0.f, ai = 0.f;
        const float2* U2 = (const float2*)Ug;
        #pragma unroll
        for (int j2 = 0; j2 < 16; j2++) {
            float2 u = U2[r * 16 + j2];
            float pr = SM[PSIo + 2 * j2], pi = SM[PSIo + 2 * j2 + 1];
            ar += u.x * pr - u.y * pi;
            ai += u.x * pi + u.y * pr;
        }
        SM[PVo + r] = ar * ar + ai * ai;
    }
    __syncthreads();
    if (tid < 4) {
        int w = tid, msk = 8 >> w;
        float e = 0.f;
        #pragma unroll
        for (int r = 0; r < 16; r++) {
            float p = SM[PVo + r];
            e += (r & msk) ? -p : p;
        }
        exps[(size_t)bidx * 4 + w] = e;
    }
}

// ---------------------------------------------------------------------------
// Kernel 2: BN batch stats (biased var) folded with gamma/beta and the output
// linear layer into out[b] = sum_w exps[b,w]*A[w] + C.  stats = {A0..A3, C}
// ---------------------------------------------------------------------------
__global__ __launch_bounds__(256) void bn_stats_kernel(
        const float* __restrict__ exps, const float* __restrict__ gamma,
        const float* __restrict__ beta, const float* __restrict__ ow,
        const float* __restrict__ ob, float* __restrict__ stats, int B) {
    int tid = threadIdx.x;
    double s0 = 0, s1 = 0, s2 = 0, s3 = 0, q0 = 0, q1 = 0, q2 = 0, q3 = 0;
    for (int i = tid; i < B; i += 256) {
        float4 e = reinterpret_cast<const float4*>(exps)[i];
        s0 += e.x; q0 += (double)e.x * e.x;
        s1 += e.y; q1 += (double)e.y * e.y;
        s2 += e.z; q2 += (double)e.z * e.z;
        s3 += e.w; q3 += (double)e.w * e.w;
    }
    __shared__ double red[8][256];
    red[0][tid] = s0; red[1][tid] = s1; red[2][tid] = s2; red[3][tid] = s3;
    red[4][tid] = q0; red[5][tid] = q1; red[6][tid] = q2; red[7][tid] = q3;
    __syncthreads();
    for (int st = 128; st > 0; st >>= 1) {
        if (tid < st)
            for (int k = 0; k < 8; k++) red[k][tid] += red[k][tid + st];
        __syncthreads();
    }
    if (tid == 0) {
        double C = (double)ob[0];
        for (int w = 0; w < 4; w++) {
            double mean = red[w][0] / (double)B;
            double var  = red[4 + w][0] / (double)B - mean * mean;
            double inv  = 1.0 / sqrt(var + 1e-5);
            double scale = (double)gamma[w] * inv;
            stats[w] = (float)(scale * (double)ow[w]);
            C += ((double)beta[w] - mean * scale) * (double)ow[w];
        }
        stats[4] = (float)C;
    }
}

__global__ __launch_bounds__(256) void out_kernel(
        const float* __restrict__ exps, const float* __restrict__ stats,
        float* __restrict__ out, int B) {
    int b = blockIdx.x * 256 + threadIdx.x;
    if (b >= B) return;
    float4 e = reinterpret_cast<const float4*>(exps)[b];
    out[b] = fmaf(e.x, stats[0],
             fmaf(e.y, stats[1],
             fmaf(e.z, stats[2],
             fmaf(e.w, stats[3], stats[4]))));
}

// ---------------------------------------------------------------------------
extern "C" void kernel_launch(void* const* d_in, const int* in_sizes, int n_in,
                              void* d_out, int out_size, void* d_ws, size_t ws_size,
                              hipStream_t stream) {
    const float* x   = (const float*)d_in[0];
    const float* c1w = (const float*)d_in[1];
    const float* c1b = (const float*)d_in[2];
    const float* c2w = (const float*)d_in[3];
    const float* c2b = (const float*)d_in[4];
    const float* fcw = (const float*)d_in[5];
    const float* fcb = (const float*)d_in[6];
    const float* qrx = (const float*)d_in[7];
    const float* qry = (const float*)d_in[8];
    const float* qrz = (const float*)d_in[9];
    const float* rl  = (const float*)d_in[10];
    const float* gmm = (const float*)d_in[11];
    const float* bta = (const float*)d_in[12];
    const float* ow  = (const float*)d_in[13];
    const float* ob  = (const float*)d_in[14];
    float* out = (float*)d_out;
    const int B = in_sizes[0] / 784;
    if (B <= 0) return;

    Ops37 ops;
    build_ops_host(&ops);

    float* ws    = (float*)d_ws;
    float* U     = ws;                      // 512 floats
    float* exps  = ws + 512;                // B*4 floats (16B aligned)
    float* stats = ws + 512 + 4 * (size_t)B;// 5 floats

    build_u_kernel<<<dim3(1), dim3(64), 0, stream>>>(rl, qrx, qry, qrz, U, ops);
    fused_fwd_kernel<<<dim3(B), dim3(128), 0, stream>>>(
        x, c1w, c1b, c2w, c2b, fcw, fcb, U, exps);
    bn_stats_kernel<<<dim3(1), dim3(256), 0, stream>>>(exps, gmm, bta, ow, ob, stats, B);
    out_kernel<<<dim3((B + 255) / 256), dim3(256), 0, stream>>>(exps, stats, out, B);
}